// Round 1
// baseline (139.186 us; speedup 1.0000x reference)
//
#include <hip/hip_runtime.h>
#include <stdint.h>

#define B_ 4096
#define D_ 1024
#define TINV 10.0f
#define LOG2E 1.4426950408889634f
#define KE (TINV * LOG2E)

typedef __bf16 bf16x8 __attribute__((ext_vector_type(8)));
typedef float f32x4 __attribute__((ext_vector_type(4)));

__device__ __forceinline__ unsigned short f2bf(float x) {
  uint32_t b = __float_as_uint(x);
  b += 0x7FFF + ((b >> 16) & 1);   // RNE
  return (unsigned short)(b >> 16);
}

__device__ __forceinline__ void gload16(const void* g, void* l) {
  __builtin_amdgcn_global_load_lds(
      (const __attribute__((address_space(1))) uint32_t*)g,
      (__attribute__((address_space(3))) uint32_t*)l, 16, 0, 0);
}

// ---------------- K1: L2-normalize rows, emit bf16 ----------------
__global__ __launch_bounds__(256) void k_normalize(const float* __restrict__ zis,
                                                   const float* __restrict__ zjs,
                                                   unsigned short* __restrict__ Abf,
                                                   unsigned short* __restrict__ Bbf) {
  int r = blockIdx.x;
  const float* src;
  unsigned short* dst;
  if (r < B_) { src = zis + (size_t)r * D_; dst = Abf + (size_t)r * D_; }
  else        { src = zjs + (size_t)(r - B_) * D_; dst = Bbf + (size_t)(r - B_) * D_; }
  int t = threadIdx.x;
  float4 v = reinterpret_cast<const float4*>(src)[t];
  float ss = v.x*v.x + v.y*v.y + v.z*v.z + v.w*v.w;
  #pragma unroll
  for (int o = 32; o >= 1; o >>= 1) ss += __shfl_down(ss, o);
  __shared__ float red[4];
  if ((t & 63) == 0) red[t >> 6] = ss;
  __syncthreads();
  float sc = rsqrtf(red[0] + red[1] + red[2] + red[3]);
  ushort4 o4;
  o4.x = f2bf(v.x * sc); o4.y = f2bf(v.y * sc);
  o4.z = f2bf(v.z * sc); o4.w = f2bf(v.w * sc);
  reinterpret_cast<ushort4*>(dst)[t] = o4;
}

// ---------------- K2: sim = A * B^T  (bf16 MFMA, m97 structure) ----------------
// 128x128 tile, BK=32, 4 waves (2x2), each wave 64x64 via 4x4 16x16x32 frags.
__global__ __launch_bounds__(256) void k_gemm(const unsigned short* __restrict__ A,
                                              const unsigned short* __restrict__ B,
                                              float* __restrict__ C) {
  __shared__ unsigned short As[128 * 32];
  __shared__ unsigned short Bs[128 * 32];
  const int tid = threadIdx.x;
  const int wid = tid >> 6;
  const int lane = tid & 63;
  const int wr = wid >> 1, wc = wid & 1;
  const int by = blockIdx.y, bx = blockIdx.x;

  f32x4 acc[4][4] = {};

  const int lrow = lane >> 2;        // 0..15 within chunk
  const int lcol = (lane & 3) * 8;   // k offset (elements)
  const int frow = lane & 15;
  const int fcol = (lane >> 4) * 8;

  for (int k0 = 0; k0 < D_; k0 += 32) {
    #pragma unroll
    for (int i = 0; i < 2; ++i) {
      int chunk = i * 4 + wid;       // 0..7 ; 1KB (16 rows) each
      int r = chunk * 16 + lrow;     // 0..127
      gload16(A + (size_t)(by * 128 + r) * D_ + k0 + lcol, &As[chunk * 512]);
      gload16(B + (size_t)(bx * 128 + r) * D_ + k0 + lcol, &Bs[chunk * 512]);
    }
    __syncthreads();   // drains vmcnt: LDS tiles valid for all waves
    bf16x8 af[4], bfr[4];
    #pragma unroll
    for (int m = 0; m < 4; ++m)
      af[m] = *reinterpret_cast<const bf16x8*>(&As[(wr*64 + m*16 + frow) * 32 + fcol]);
    #pragma unroll
    for (int n = 0; n < 4; ++n)
      bfr[n] = *reinterpret_cast<const bf16x8*>(&Bs[(wc*64 + n*16 + frow) * 32 + fcol]);
    #pragma unroll
    for (int m = 0; m < 4; ++m)
      #pragma unroll
      for (int n = 0; n < 4; ++n)
        acc[m][n] = __builtin_amdgcn_mfma_f32_16x16x32_bf16(af[m], bfr[n], acc[m][n], 0, 0, 0);
    __syncthreads();   // all reads done before next stage overwrites
  }

  const int crow0 = by * 128 + wr * 64;
  const int ccol0 = bx * 128 + wc * 64;
  #pragma unroll
  for (int m = 0; m < 4; ++m)
    #pragma unroll
    for (int n = 0; n < 4; ++n)
      #pragma unroll
      for (int q = 0; q < 4; ++q) {
        int rr = crow0 + m*16 + (lane >> 4)*4 + q;   // row = (lane>>4)*4+reg  [m89/m91]
        int cc = ccol0 + n*16 + (lane & 15);         // col = lane&15
        C[(size_t)rr * B_ + cc] = acc[m][n][q];
      }
}

// ---------------- K3: fused row pipeline ----------------
// rowmax + diag + exp-sums + image_loss, one read of sim (row staged in LDS).
__global__ __launch_bounds__(256) void k_rowpass(const float* __restrict__ sim,
    const float* __restrict__ bI, const float* __restrict__ sI,
    const int* __restrict__ ids,
    float* __restrict__ diag, float* __restrict__ LI) {
  __shared__ float row[B_];
  __shared__ float red[16];
  const int i = blockIdx.x;
  const int t = threadIdx.x;
  const float* sr = sim + (size_t)i * B_;
  float mx = -3.4e38f;
  #pragma unroll
  for (int c = 0; c < 4; ++c) {
    float4 x = reinterpret_cast<const float4*>(sr)[c * 256 + t];
    reinterpret_cast<float4*>(row)[c * 256 + t] = x;
    mx = fmaxf(mx, fmaxf(fmaxf(x.x, x.y), fmaxf(x.z, x.w)));
  }
  #pragma unroll
  for (int o = 32; o >= 1; o >>= 1) mx = fmaxf(mx, __shfl_down(mx, o));
  if ((t & 63) == 0) red[t >> 6] = mx;
  __syncthreads();
  float rowmax = fmaxf(fmaxf(red[0], red[1]), fmaxf(red[2], red[3]));
  float dg = row[i];
  float oldb = bI[ids[i]];
  float newb = fmaxf((rowmax - dg) * TINV, oldb);   // includes idd_ii = 0 automatically
  float c2 = (dg * TINV + newb) * LOG2E;
  float s1 = 0.f, s2 = 0.f;
  for (int j = t; j < B_; j += 256) {
    if (j == i) continue;
    float s = row[j];
    float e = exp2f(s * KE - c2);
    s1 += e;
    s2 += e * (s - dg);
  }
  #pragma unroll
  for (int o = 32; o >= 1; o >>= 1) { s1 += __shfl_down(s1, o); s2 += __shfl_down(s2, o); }
  if ((t & 63) == 0) { red[4 + (t >> 6)] = s1; red[8 + (t >> 6)] = s2; }
  __syncthreads();
  if (t == 0) {
    float S1 = red[4] + red[5] + red[6] + red[7];
    float S2 = red[8] + red[9] + red[10] + red[11];
    float g = S1 / (float)(B_ - 1);
    float sn = 0.2f * sI[ids[i]] * exp2f((oldb - newb) * LOG2E) + 0.8f * g;
    float li = S2 / fmaxf(sn, 1e-14f) / (float)(B_ - 1);
    diag[i] = dg;
    LI[i] = li;
  }
}

// ---------------- K4: column max partials ----------------
__global__ __launch_bounds__(256) void k_colmax(const float* __restrict__ sim,
                                                float* __restrict__ cmax_p) {
  int jv = blockIdx.x * 256 + threadIdx.x;     // float4-column index 0..1023
  int r0 = blockIdx.y * 64;
  const float4* p = reinterpret_cast<const float4*>(sim) + (size_t)r0 * (B_/4) + jv;
  float4 m = make_float4(-3.4e38f, -3.4e38f, -3.4e38f, -3.4e38f);
  for (int r = 0; r < 64; ++r) {
    float4 x = p[(size_t)r * (B_/4)];
    m.x = fmaxf(m.x, x.x); m.y = fmaxf(m.y, x.y);
    m.z = fmaxf(m.z, x.z); m.w = fmaxf(m.w, x.w);
  }
  reinterpret_cast<float4*>(cmax_p)[(size_t)blockIdx.y * (B_/4) + jv] = m;
}

// ---------------- K5: per-column prep (new_b_T, exp offsets) ----------------
__global__ __launch_bounds__(256) void k_prepT(const float* __restrict__ cmax_p,
    const float* __restrict__ diag, const float* __restrict__ bT,
    const int* __restrict__ ids,
    float* __restrict__ cT2, float* __restrict__ ebT) {
  int j = blockIdx.x * 256 + threadIdx.x;      // grid 16
  float m = -3.4e38f;
  for (int p = 0; p < 64; ++p) m = fmaxf(m, cmax_p[(size_t)p * B_ + j]);
  float dg = diag[j];
  float oldb = bT[ids[j]];
  float newb = fmaxf((m - dg) * TINV, oldb);
  cT2[j] = (dg * TINV + newb) * LOG2E;
  ebT[j] = exp2f((oldb - newb) * LOG2E);
}

// ---------------- K6: column exp-sum partials ----------------
__global__ __launch_bounds__(256) void k_colsum(const float* __restrict__ sim,
    const float* __restrict__ cT2, const float* __restrict__ diag,
    float* __restrict__ S1T_p, float* __restrict__ S2T_p) {
  int jv = blockIdx.x * 256 + threadIdx.x;
  int j0 = jv * 4;
  int r0 = blockIdx.y * 64;
  float4 c2 = reinterpret_cast<const float4*>(cT2)[jv];
  float4 dg = reinterpret_cast<const float4*>(diag)[jv];
  const float4* p = reinterpret_cast<const float4*>(sim) + (size_t)r0 * (B_/4) + jv;
  float4 s1 = make_float4(0,0,0,0), s2 = make_float4(0,0,0,0);
  for (int r = 0; r < 64; ++r) {
    int rr = r0 + r;
    float4 x = p[(size_t)r * (B_/4)];
    float e0 = exp2f(x.x * KE - c2.x);
    float e1 = exp2f(x.y * KE - c2.y);
    float e2 = exp2f(x.z * KE - c2.z);
    float e3 = exp2f(x.w * KE - c2.w);
    if (rr != j0    ) { s1.x += e0; s2.x += e0 * (x.x - dg.x); }
    if (rr != j0 + 1) { s1.y += e1; s2.y += e1 * (x.y - dg.y); }
    if (rr != j0 + 2) { s1.z += e2; s2.z += e2 * (x.z - dg.z); }
    if (rr != j0 + 3) { s1.w += e3; s2.w += e3 * (x.w - dg.w); }
  }
  reinterpret_cast<float4*>(S1T_p)[(size_t)blockIdx.y * (B_/4) + jv] = s1;
  reinterpret_cast<float4*>(S2T_p)[(size_t)blockIdx.y * (B_/4) + jv] = s2;
}

// ---------------- K7: text loss + combine, block partials ----------------
__global__ __launch_bounds__(256) void k_final1(const float* __restrict__ S1T_p,
    const float* __restrict__ S2T_p, const float* __restrict__ ebT,
    const float* __restrict__ sT, const int* __restrict__ ids,
    const float* __restrict__ LI, float* __restrict__ partial) {
  int j = blockIdx.x * 256 + threadIdx.x;      // grid 16
  float s1 = 0.f, s2 = 0.f;
  for (int p = 0; p < 64; ++p) {
    s1 += S1T_p[(size_t)p * B_ + j];
    s2 += S2T_p[(size_t)p * B_ + j];
  }
  float g = s1 / (float)(B_ - 1);
  float sn = 0.2f * sT[ids[j]] * ebT[j] + 0.8f * g;
  float lt = s2 / fmaxf(sn, 1e-14f) / (float)(B_ - 1);
  float v = (0.5f * LI[j] + 0.5f * lt) * (1.0f / (float)B_);
  #pragma unroll
  for (int o = 32; o >= 1; o >>= 1) v += __shfl_down(v, o);
  __shared__ float red[4];
  int t = threadIdx.x;
  if ((t & 63) == 0) red[t >> 6] = v;
  __syncthreads();
  if (t == 0) partial[blockIdx.x] = red[0] + red[1] + red[2] + red[3];
}

__global__ void k_final2(const float* __restrict__ partial, float* __restrict__ out) {
  float v = (threadIdx.x < 16) ? partial[threadIdx.x] : 0.f;
  #pragma unroll
  for (int o = 32; o >= 1; o >>= 1) v += __shfl_down(v, o);
  if (threadIdx.x == 0) out[0] = v;
}

extern "C" void kernel_launch(void* const* d_in, const int* in_sizes, int n_in,
                              void* d_out, int out_size, void* d_ws, size_t ws_size,
                              hipStream_t stream) {
  const float* zis = (const float*)d_in[0];
  const float* zjs = (const float*)d_in[1];
  const float* s_I = (const float*)d_in[2];
  const float* s_T = (const float*)d_in[3];
  const float* b_I = (const float*)d_in[4];
  const float* b_T = (const float*)d_in[5];
  const int*   ids = (const int*)d_in[6];

  char* ws = (char*)d_ws;
  size_t off = 0;
  auto alloc = [&](size_t bytes) -> void* {
    void* p = ws + off;
    off = (off + bytes + 255) & ~(size_t)255;
    return p;
  };
  unsigned short* Abf = (unsigned short*)alloc((size_t)B_ * D_ * 2);   // 8 MB
  unsigned short* Bbf = (unsigned short*)alloc((size_t)B_ * D_ * 2);   // 8 MB
  float* sim    = (float*)alloc((size_t)B_ * B_ * 4);                  // 64 MB
  float* diag   = (float*)alloc(B_ * 4);
  float* LI     = (float*)alloc(B_ * 4);
  float* cmax_p = (float*)alloc((size_t)64 * B_ * 4);                  // 1 MB
  float* cT2    = (float*)alloc(B_ * 4);
  float* ebT    = (float*)alloc(B_ * 4);
  float* S1T_p  = (float*)alloc((size_t)64 * B_ * 4);
  float* S2T_p  = (float*)alloc((size_t)64 * B_ * 4);
  float* partial = (float*)alloc(16 * 4);

  k_normalize<<<2 * B_, 256, 0, stream>>>(zis, zjs, Abf, Bbf);
  k_gemm<<<dim3(32, 32), 256, 0, stream>>>(Abf, Bbf, sim);
  k_rowpass<<<B_, 256, 0, stream>>>(sim, b_I, s_I, ids, diag, LI);
  k_colmax<<<dim3(4, 64), 256, 0, stream>>>(sim, cmax_p);
  k_prepT<<<dim3(16), 256, 0, stream>>>(cmax_p, diag, b_T, ids, cT2, ebT);
  k_colsum<<<dim3(4, 64), 256, 0, stream>>>(sim, cT2, diag, S1T_p, S2T_p);
  k_final1<<<dim3(16), 256, 0, stream>>>(S1T_p, S2T_p, ebT, s_T, ids, LI, partial);
  k_final2<<<1, 64, 0, stream>>>(partial, (float*)d_out);
}

// Round 2
// 129.732 us; speedup vs baseline: 1.0729x; 1.0729x over previous
//
#include <hip/hip_runtime.h>
#include <stdint.h>

#define B_ 4096
#define D_ 1024
#define TINV 10.0f
#define LOG2E 1.4426950408889634f
#define KE (TINV * LOG2E)
#define INV_BM1 (1.0f / 4095.0f)

typedef __bf16 bf16x8 __attribute__((ext_vector_type(8)));
typedef float f32x4 __attribute__((ext_vector_type(4)));

__device__ __forceinline__ unsigned short f2bf(float x) {
  uint32_t b = __float_as_uint(x);
  b += 0x7FFF + ((b >> 16) & 1);   // RNE
  return (unsigned short)(b >> 16);
}

__device__ __forceinline__ void gload16(const void* g, void* l) {
  __builtin_amdgcn_global_load_lds(
      (const __attribute__((address_space(1))) uint32_t*)g,
      (__attribute__((address_space(3))) uint32_t*)l, 16, 0, 0);
}

// ---------------- K1: L2-normalize rows, emit bf16 ----------------
__global__ __launch_bounds__(256) void k_normalize(const float* __restrict__ zis,
                                                   const float* __restrict__ zjs,
                                                   unsigned short* __restrict__ Abf,
                                                   unsigned short* __restrict__ Bbf) {
  int r = blockIdx.x;
  const float* src;
  unsigned short* dst;
  if (r < B_) { src = zis + (size_t)r * D_; dst = Abf + (size_t)r * D_; }
  else        { src = zjs + (size_t)(r - B_) * D_; dst = Bbf + (size_t)(r - B_) * D_; }
  int t = threadIdx.x;
  float4 v = reinterpret_cast<const float4*>(src)[t];
  float ss = v.x*v.x + v.y*v.y + v.z*v.z + v.w*v.w;
  #pragma unroll
  for (int o = 32; o >= 1; o >>= 1) ss += __shfl_down(ss, o);
  __shared__ float red[4];
  if ((t & 63) == 0) red[t >> 6] = ss;
  __syncthreads();
  float sc = rsqrtf(red[0] + red[1] + red[2] + red[3]);
  ushort4 o4;
  o4.x = f2bf(v.x * sc); o4.y = f2bf(v.y * sc);
  o4.z = f2bf(v.z * sc); o4.w = f2bf(v.w * sc);
  reinterpret_cast<ushort4*>(dst)[t] = o4;
}

// ---------------- K2: sim = A * B^T + per-tile row/col max partials ----------------
// 128x128 tile, BK=32, 4 waves (2x2), each wave 64x64 via 4x4 16x16x32 frags.
__global__ __launch_bounds__(256) void k_gemm(const unsigned short* __restrict__ A,
                                              const unsigned short* __restrict__ B,
                                              float* __restrict__ C,
                                              float* __restrict__ rmax_p,
                                              float* __restrict__ cmax_p) {
  __shared__ unsigned short As[128 * 32];
  __shared__ unsigned short Bs[128 * 32];
  __shared__ float rowLds[256];   // [wc][128 rows]
  __shared__ float colLds[256];   // [wr][128 cols]
  const int tid = threadIdx.x;
  const int wid = tid >> 6;
  const int lane = tid & 63;
  const int wr = wid >> 1, wc = wid & 1;
  const int by = blockIdx.y, bx = blockIdx.x;

  f32x4 acc[4][4] = {};

  const int lrow = lane >> 2;        // 0..15 within chunk
  const int lcol = (lane & 3) * 8;   // k offset (elements)
  const int frow = lane & 15;
  const int fcol = (lane >> 4) * 8;

  for (int k0 = 0; k0 < D_; k0 += 32) {
    #pragma unroll
    for (int i = 0; i < 2; ++i) {
      int chunk = i * 4 + wid;       // 0..7 ; 1KB (16 rows) each
      int r = chunk * 16 + lrow;     // 0..127
      gload16(A + (size_t)(by * 128 + r) * D_ + k0 + lcol, &As[chunk * 512]);
      gload16(B + (size_t)(bx * 128 + r) * D_ + k0 + lcol, &Bs[chunk * 512]);
    }
    __syncthreads();
    bf16x8 af[4], bfr[4];
    #pragma unroll
    for (int m = 0; m < 4; ++m)
      af[m] = *reinterpret_cast<const bf16x8*>(&As[(wr*64 + m*16 + frow) * 32 + fcol]);
    #pragma unroll
    for (int n = 0; n < 4; ++n)
      bfr[n] = *reinterpret_cast<const bf16x8*>(&Bs[(wc*64 + n*16 + frow) * 32 + fcol]);
    #pragma unroll
    for (int m = 0; m < 4; ++m)
      #pragma unroll
      for (int n = 0; n < 4; ++n)
        acc[m][n] = __builtin_amdgcn_mfma_f32_16x16x32_bf16(af[m], bfr[n], acc[m][n], 0, 0, 0);
    __syncthreads();
  }

  // --- epilogue: per-tile row max partials ---
  #pragma unroll
  for (int m = 0; m < 4; ++m)
    #pragma unroll
    for (int q = 0; q < 4; ++q) {
      float v = fmaxf(fmaxf(acc[m][0][q], acc[m][1][q]), fmaxf(acc[m][2][q], acc[m][3][q]));
      v = fmaxf(v, __shfl_xor(v, 1));
      v = fmaxf(v, __shfl_xor(v, 2));
      v = fmaxf(v, __shfl_xor(v, 4));
      v = fmaxf(v, __shfl_xor(v, 8));
      // lanes 0,16,32,48 hold the max for row m*16 + hi*4 + q
      if ((lane & 15) == 0)
        rowLds[wc * 128 + wr * 64 + m * 16 + (lane >> 4) * 4 + q] = v;
    }
  // --- per-tile col max partials ---
  #pragma unroll
  for (int n = 0; n < 4; ++n) {
    float v = -3.4e38f;
    #pragma unroll
    for (int m = 0; m < 4; ++m)
      #pragma unroll
      for (int q = 0; q < 4; ++q) v = fmaxf(v, acc[m][n][q]);
    v = fmaxf(v, __shfl_xor(v, 16));
    v = fmaxf(v, __shfl_xor(v, 32));
    if (lane < 16) colLds[wr * 128 + wc * 64 + n * 16 + lane] = v;
  }
  __syncthreads();
  if (tid < 128)
    rmax_p[(size_t)bx * B_ + by * 128 + tid] = fmaxf(rowLds[tid], rowLds[128 + tid]);
  else {
    int t2 = tid - 128;
    cmax_p[(size_t)by * B_ + bx * 128 + t2] = fmaxf(colLds[t2], colLds[128 + t2]);
  }

  // --- C store ---
  const int crow0 = by * 128 + wr * 64;
  const int ccol0 = bx * 128 + wc * 64;
  #pragma unroll
  for (int m = 0; m < 4; ++m)
    #pragma unroll
    for (int n = 0; n < 4; ++n)
      #pragma unroll
      for (int q = 0; q < 4; ++q) {
        int rr = crow0 + m*16 + (lane >> 4)*4 + q;   // row = (lane>>4)*4+reg
        int cc = ccol0 + n*16 + (lane & 15);         // col = lane&15
        C[(size_t)rr * B_ + cc] = acc[m][n][q];
      }
}

// ---------------- K3: per-row & per-col prep ----------------
// rows: blockIdx.x 0..15 ; cols: blockIdx.x 16..31
__global__ __launch_bounds__(256) void k_prep(const float* __restrict__ sim,
    const float* __restrict__ rmax_p, const float* __restrict__ cmax_p,
    const float* __restrict__ bI, const float* __restrict__ bT,
    const float* __restrict__ sI, const float* __restrict__ sT,
    const int* __restrict__ ids,
    float* __restrict__ rowC2, float* __restrict__ Fi, float* __restrict__ eDI,
    float* __restrict__ wI0, float* __restrict__ diag,
    float* __restrict__ Gj, float* __restrict__ eDT, float* __restrict__ wT0) {
  int t = threadIdx.x;
  if (blockIdx.x < 16) {
    int i = blockIdx.x * 256 + t;
    float m = -3.4e38f;
    for (int p = 0; p < 32; ++p) m = fmaxf(m, rmax_p[(size_t)p * B_ + i]);
    float dg = sim[(size_t)i * (B_ + 1)];
    float oldb = bI[ids[i]];
    float newb = fmaxf((m - dg) * TINV, oldb);
    float c2 = (dg * TINV + newb) * LOG2E;
    rowC2[i] = c2;
    Fi[i] = exp2f(c2);
    eDI[i] = exp2f(-newb * LOG2E);
    wI0[i] = 0.2f * sI[ids[i]] * exp2f((oldb - newb) * LOG2E);
    diag[i] = dg;
  } else {
    int j = (blockIdx.x - 16) * 256 + t;
    float m = -3.4e38f;
    for (int p = 0; p < 32; ++p) m = fmaxf(m, cmax_p[(size_t)p * B_ + j]);
    float dg = sim[(size_t)j * (B_ + 1)];
    float oldb = bT[ids[j]];
    float newb = fmaxf((m - dg) * TINV, oldb);
    float c2 = (dg * TINV + newb) * LOG2E;
    Gj[j] = exp2f(-c2);
    eDT[j] = exp2f(-newb * LOG2E);
    wT0[j] = 0.2f * sT[ids[j]] * exp2f((oldb - newb) * LOG2E);
  }
}

// ---------------- K4: fused single-read pass ----------------
// 256 blocks x 16 rows. Row losses finalized; col exp-sum partials written.
__global__ __launch_bounds__(256) void k_fused(const float* __restrict__ sim,
    const float* __restrict__ rowC2, const float* __restrict__ diag,
    const float* __restrict__ Fi, const float* __restrict__ Gj,
    const float* __restrict__ eDI, const float* __restrict__ wI0,
    float* __restrict__ LI, float* __restrict__ S1T_p, float* __restrict__ S2T_p) {
  const int i0 = blockIdx.x * 16;
  const int t = threadIdx.x;
  const int w = t >> 6;
  const int lane = t & 63;
  __shared__ float rowPart[16][4][2];

  float4 gj[4], dgj[4];
  #pragma unroll
  for (int c = 0; c < 4; ++c) {
    gj[c]  = reinterpret_cast<const float4*>(Gj)[t + 256 * c];
    dgj[c] = reinterpret_cast<const float4*>(diag)[t + 256 * c];
  }
  float4 cs1[4] = {}, cs2[4] = {};

  for (int r = 0; r < 16; ++r) {
    const int i = i0 + r;
    const float rC2 = rowC2[i];
    const float dgi = diag[i];
    const float fi  = Fi[i];
    float rs1 = 0.f, rs2 = 0.f;
    const float4* sr = reinterpret_cast<const float4*>(sim + (size_t)i * B_);
    #pragma unroll
    for (int c = 0; c < 4; ++c) {
      float4 x = sr[t + 256 * c];
      float fg_x = fi * gj[c].x, fg_y = fi * gj[c].y, fg_z = fi * gj[c].z, fg_w = fi * gj[c].w;
      float e0 = exp2f(x.x * KE - rC2);
      float e1 = exp2f(x.y * KE - rC2);
      float e2 = exp2f(x.z * KE - rC2);
      float e3 = exp2f(x.w * KE - rC2);
      rs1 += e0 + e1 + e2 + e3;
      rs2 += e0*(x.x - dgi) + e1*(x.y - dgi) + e2*(x.z - dgi) + e3*(x.w - dgi);
      float c0 = e0 * fg_x, c1 = e1 * fg_y, c2v = e2 * fg_z, c3 = e3 * fg_w;
      cs1[c].x += c0; cs1[c].y += c1; cs1[c].z += c2v; cs1[c].w += c3;
      cs2[c].x += c0*(x.x - dgj[c].x); cs2[c].y += c1*(x.y - dgj[c].y);
      cs2[c].z += c2v*(x.z - dgj[c].z); cs2[c].w += c3*(x.w - dgj[c].w);
    }
    #pragma unroll
    for (int o = 32; o >= 1; o >>= 1) { rs1 += __shfl_down(rs1, o); rs2 += __shfl_down(rs2, o); }
    if (lane == 0) { rowPart[r][w][0] = rs1; rowPart[r][w][1] = rs2; }
  }
  __syncthreads();
  if (t < 16) {
    const int i = i0 + t;
    float S1 = rowPart[t][0][0] + rowPart[t][1][0] + rowPart[t][2][0] + rowPart[t][3][0];
    float S2 = rowPart[t][0][1] + rowPart[t][1][1] + rowPart[t][2][1] + rowPart[t][3][1];
    S1 -= eDI[i];                    // remove diagonal term (s2 diag term is 0)
    float g = S1 * INV_BM1;
    float sn = wI0[i] + 0.8f * g;
    LI[i] = S2 / fmaxf(sn, 1e-14f) * INV_BM1;
  }
  #pragma unroll
  for (int c = 0; c < 4; ++c) {
    reinterpret_cast<float4*>(S1T_p)[(size_t)blockIdx.x * (B_/4) + t + 256 * c] = cs1[c];
    reinterpret_cast<float4*>(S2T_p)[(size_t)blockIdx.x * (B_/4) + t + 256 * c] = cs2[c];
  }
}

// ---------------- K5: column reduce + text loss + combine ----------------
__global__ __launch_bounds__(256) void k_finalT(const float* __restrict__ S1T_p,
    const float* __restrict__ S2T_p, const float* __restrict__ eDT,
    const float* __restrict__ wT0, const float* __restrict__ LI,
    float* __restrict__ partial) {
  int t = threadIdx.x;
  int j = blockIdx.x * 256 + t;
  float s1 = 0.f, s2 = 0.f;
  for (int p = 0; p < 256; ++p) {
    s1 += S1T_p[(size_t)p * B_ + j];
    s2 += S2T_p[(size_t)p * B_ + j];
  }
  s1 -= eDT[j];
  float g = s1 * INV_BM1;
  float sn = wT0[j] + 0.8f * g;
  float lt = s2 / fmaxf(sn, 1e-14f) * INV_BM1;
  float v = (0.5f * LI[j] + 0.5f * lt) * (1.0f / (float)B_);
  #pragma unroll
  for (int o = 32; o >= 1; o >>= 1) v += __shfl_down(v, o);
  __shared__ float red[4];
  if ((t & 63) == 0) red[t >> 6] = v;
  __syncthreads();
  if (t == 0) partial[blockIdx.x] = red[0] + red[1] + red[2] + red[3];
}

__global__ void k_final2(const float* __restrict__ partial, float* __restrict__ out) {
  float v = (threadIdx.x < 16) ? partial[threadIdx.x] : 0.f;
  #pragma unroll
  for (int o = 32; o >= 1; o >>= 1) v += __shfl_down(v, o);
  if (threadIdx.x == 0) out[0] = v;
}

extern "C" void kernel_launch(void* const* d_in, const int* in_sizes, int n_in,
                              void* d_out, int out_size, void* d_ws, size_t ws_size,
                              hipStream_t stream) {
  const float* zis = (const float*)d_in[0];
  const float* zjs = (const float*)d_in[1];
  const float* s_I = (const float*)d_in[2];
  const float* s_T = (const float*)d_in[3];
  const float* b_I = (const float*)d_in[4];
  const float* b_T = (const float*)d_in[5];
  const int*   ids = (const int*)d_in[6];

  char* ws = (char*)d_ws;
  size_t off = 0;
  auto alloc = [&](size_t bytes) -> void* {
    void* p = ws + off;
    off = (off + bytes + 255) & ~(size_t)255;
    return p;
  };
  unsigned short* Abf = (unsigned short*)alloc((size_t)B_ * D_ * 2);   // 8 MB
  unsigned short* Bbf = (unsigned short*)alloc((size_t)B_ * D_ * 2);   // 8 MB
  float* sim    = (float*)alloc((size_t)B_ * B_ * 4);                  // 64 MB
  float* rmax_p = (float*)alloc((size_t)32 * B_ * 4);                  // 512 KB
  float* cmax_p = (float*)alloc((size_t)32 * B_ * 4);                  // 512 KB
  float* rowC2  = (float*)alloc(B_ * 4);
  float* Fi     = (float*)alloc(B_ * 4);
  float* eDI    = (float*)alloc(B_ * 4);
  float* wI0    = (float*)alloc(B_ * 4);
  float* diag   = (float*)alloc(B_ * 4);
  float* Gj     = (float*)alloc(B_ * 4);
  float* eDT    = (float*)alloc(B_ * 4);
  float* wT0    = (float*)alloc(B_ * 4);
  float* LI     = (float*)alloc(B_ * 4);
  float* partial = (float*)alloc(16 * 4);
  // col partials alias the bf16 staging buffers (dead after k_gemm)
  float* S1T_p  = (float*)Abf;                                         // 4 MB used
  float* S2T_p  = (float*)Bbf;                                         // 4 MB used

  k_normalize<<<2 * B_, 256, 0, stream>>>(zis, zjs, Abf, Bbf);
  k_gemm<<<dim3(32, 32), 256, 0, stream>>>(Abf, Bbf, sim, rmax_p, cmax_p);
  k_prep<<<32, 256, 0, stream>>>(sim, rmax_p, cmax_p, b_I, b_T, s_I, s_T, ids,
                                 rowC2, Fi, eDI, wI0, diag, Gj, eDT, wT0);
  k_fused<<<256, 256, 0, stream>>>(sim, rowC2, diag, Fi, Gj, eDI, wI0,
                                   LI, S1T_p, S2T_p);
  k_finalT<<<16, 256, 0, stream>>>(S1T_p, S2T_p, eDT, wT0, LI, partial);
  k_final2<<<1, 64, 0, stream>>>(partial, (float*)d_out);
}